// Round 2
// baseline (523.899 us; speedup 1.0000x reference)
//
#include <hip/hip_runtime.h>
#include <hip/hip_bf16.h>
#include <cstdint>

// KAN MLP fused: layers 256->512->512->256, B=8192, cubic B-splines (uniform
// grid h=0.25, 11 bases), BN fused into last GEMM.
//
// Round-2 design: expansion (gelu + spline bases) fused INTO the GEMM.
// Per layer: C[M,N] = sum_feat [gelu(x)|bases(x)]_12 . Wpk, BK = 96 = 8 feats.
//  - A-tile: threads read X fp32 (float2/thread), expand in regs during the
//    previous chunk's MFMA phase, ds_write_b128 into chunk-major LDS.
//  - B-tile: register-prefetched from a pre-swizzled packed W (coalesced),
//    ds_write_b128 into chunk-major LDS.
//  - Split-K (2/2/4) -> 1024 blocks/layer = 4 blocks/CU; fp32 atomicAdd.
//
// Workspace: W0@0 (3.1MB), W1@3145728 (6.3MB), W2@9437184 (3.1MB),
//            H1@12582912 (16MB), H2@29360128 (16MB).  Total ~46MB.

typedef unsigned short ushort_t;
typedef __bf16 bf16x8 __attribute__((ext_vector_type(8)));
typedef float f32x4 __attribute__((ext_vector_type(4)));

__device__ __forceinline__ ushort_t f2bf(float f) {
    __bf16 h = (__bf16)f;  // RNE
    return __builtin_bit_cast(ushort_t, h);
}

// x -> [gelu, b0..b10] as 12 bf16 (uniform-grid cubic B-spline closed form)
__device__ __forceinline__ void expand12(float x, ushort_t* out) {
    float gelu = 0.5f * x * (1.0f + erff(x * 0.70710678118654752440f));
    float xs = (x + 1.75f) * 4.0f;
    float fs = floorf(xs);
    int   s  = (int)fs;
    float u  = xs - fs;
    bool  inr = (s >= 0) && (s <= 13);
    float u2 = u * u, u3 = u2 * u, om = 1.0f - u;
    const float c6 = 1.0f / 6.0f;
    float w0 = om * om * om * c6;
    float w1 = (3.0f * u3 - 6.0f * u2 + 4.0f) * c6;
    float w2 = (-3.0f * u3 + 3.0f * u2 + 3.0f * u + 1.0f) * c6;
    float w3 = u3 * c6;
    out[0] = f2bf(gelu);
#pragma unroll
    for (int j = 0; j < 11; ++j) {
        float v = 0.0f;
        if (inr) {
            if (j == s - 3)      v = w0;
            else if (j == s - 2) v = w1;
            else if (j == s - 1) v = w2;
            else if (j == s)     v = w3;
        }
        out[1 + j] = f2bf(v);
    }
}

// ---------------------------------------------------------------------------
// Pack W into chunk-major tiles: chunk id c = ((nb*KB + kb)*12 + kc)*64 + n,
// chunk = 8 bf16 of W[n_g = nb*64+n][k = kb*96 + kc*8 .. +7], where
// k = feat*12 + comp (comp 0 = base weight, 1..11 = spline weights).
// ---------------------------------------------------------------------------
__global__ __launch_bounds__(256) void pack_w_kernel(
    const float* __restrict__ bw, const float* __restrict__ sw,
    ushort_t* __restrict__ W, int fin, int KB, int total_chunks)
{
    int c = blockIdx.x * 256 + threadIdx.x;
    if (c >= total_chunks) return;
    int n    = c & 63;
    int tmp  = c >> 6;
    int kc   = tmp % 12;
    int rest = tmp / 12;
    int kb   = rest % KB;
    int nb   = rest / KB;
    int n_g  = nb * 64 + n;
    int k0   = kb * 96 + kc * 8;
    union { ushort_t us[8]; uint4 v; } pk;
#pragma unroll
    for (int jj = 0; jj < 8; ++jj) {
        int k = k0 + jj;
        int i = k / 12, comp = k % 12;
        float val = (comp == 0) ? bw[(size_t)n_g * fin + i]
                                : sw[((size_t)n_g * fin + i) * 11 + comp - 1];
        pk.us[jj] = f2bf(val);
    }
    *(uint4*)(W + (size_t)c * 8) = pk.v;
}

__global__ __launch_bounds__(256) void zero_kernel(float4* __restrict__ p, int n4) {
    int i = blockIdx.x * 256 + threadIdx.x;
    int stride = gridDim.x * 256;
    for (; i < n4; i += stride) p[i] = make_float4(0.f, 0.f, 0.f, 0.f);
}

// ---------------------------------------------------------------------------
// Fused KAN GEMM. Tile 128(M) x 64(N), BK = 96 (8 features), 4 waves (2x2,
// wave = 64x32). Chunk-major LDS: As[kc][m] / Bs[kc][n] in 16B chunks ->
// conflict-free ds_read_b128 / ds_write_b128.
//   A frag: lane holds A[m=l15][k=q*8+j];  C/D: D[m=q*4+r][n=l15].
// Split-K over blockIdx.z, fp32 atomicAdd epilogue (BN bias on z==0 only).
// ---------------------------------------------------------------------------
template <bool FUSE_BN>
__global__ __launch_bounds__(256, 4) void kan_gemm_kernel(
    const float* __restrict__ X,      // M x fin fp32
    const ushort_t* __restrict__ Wp,  // packed chunks
    float* __restrict__ C,            // M x N fp32 (pre-zeroed, atomics)
    int fin, int N, int KB, int cps,
    const float* __restrict__ gamma, const float* __restrict__ beta,
    const float* __restrict__ mean,  const float* __restrict__ var)
{
    __shared__ __align__(16) ushort_t As[12 * 128 * 8];  // 24 KB
    __shared__ __align__(16) ushort_t Bs[12 * 64 * 8];   // 12 KB

    const int t   = threadIdx.x;
    const int l   = t & 63;
    const int w   = t >> 6;
    const int wm  = w >> 1;
    const int wn  = w & 1;
    const int l15 = l & 15;
    const int q   = l >> 4;
    const int blockM = blockIdx.x * 128;
    const int nb = blockIdx.y;
    const int z  = blockIdx.z;
    const int kb0 = z * cps, kb1 = kb0 + cps;

    const int fp = t & 3;        // feature-pair 0..3 within chunk
    const int mx = t >> 2;       // row 0..63 (and +64)

    f32x4 acc[4][2];
#pragma unroll
    for (int i = 0; i < 4; ++i)
#pragma unroll
        for (int j = 0; j < 2; ++j) acc[i][j] = (f32x4){0.f, 0.f, 0.f, 0.f};

    union { ushort_t us[24]; uint4 v[3]; } er[2];
    uint4  br[3];
    float2 xr[2];

    const float* Xrow0 = X + (size_t)(blockM + mx) * fin + 2 * fp;
    const float* Xrow1 = Xrow0 + (size_t)64 * fin;
    const ushort_t* Wbase = Wp + (size_t)nb * KB * 768 * 8 + (size_t)t * 8;

    // prologue: chunk kb0
    {
        xr[0] = *(const float2*)(Xrow0 + kb0 * 8);
        xr[1] = *(const float2*)(Xrow1 + kb0 * 8);
        const ushort_t* wsrc = Wbase + (size_t)kb0 * 768 * 8;
        br[0] = *(const uint4*)(wsrc);
        br[1] = *(const uint4*)(wsrc + 2048);
        br[2] = *(const uint4*)(wsrc + 4096);
        expand12(xr[0].x, er[0].us);
        expand12(xr[0].y, er[0].us + 12);
        expand12(xr[1].x, er[1].us);
        expand12(xr[1].y, er[1].us + 12);
    }

    for (int kb = kb0; kb < kb1; ++kb) {
        __syncthreads();  // previous chunk's LDS readers done
        // stage A (expansion regs) and B (prefetched regs) -> LDS
#pragma unroll
        for (int i = 0; i < 2; ++i) {
            int m = mx + 64 * i;
#pragma unroll
            for (int j = 0; j < 3; ++j)
                *(uint4*)&As[(size_t)((3 * fp + j) * 128 + m) * 8] = er[i].v[j];
        }
#pragma unroll
        for (int j = 0; j < 3; ++j)
            *(uint4*)&Bs[(size_t)(j * 256 + t) * 8] = br[j];
        __syncthreads();  // writes visible

        const bool more = (kb + 1 < kb1);
        if (more) {  // prefetch next chunk; latency covered by MFMA phase
            xr[0] = *(const float2*)(Xrow0 + (kb + 1) * 8);
            xr[1] = *(const float2*)(Xrow1 + (kb + 1) * 8);
            const ushort_t* wsrc = Wbase + (size_t)(kb + 1) * 768 * 8;
            br[0] = *(const uint4*)(wsrc);
            br[1] = *(const uint4*)(wsrc + 2048);
            br[2] = *(const uint4*)(wsrc + 4096);
        }

        // MFMA phase: 3 k-steps x (4 mi x 2 ni) = 24 MFMA/wave
#pragma unroll
        for (int ks = 0; ks < 3; ++ks) {
            bf16x8 af[4], bf[2];
#pragma unroll
            for (int mi = 0; mi < 4; ++mi) {
                int m = wm * 64 + mi * 16 + l15;
                af[mi] = *(const bf16x8*)&As[(size_t)((ks * 4 + q) * 128 + m) * 8];
            }
#pragma unroll
            for (int ni = 0; ni < 2; ++ni) {
                int n = wn * 32 + ni * 16 + l15;
                bf[ni] = *(const bf16x8*)&Bs[(size_t)((ks * 4 + q) * 64 + n) * 8];
            }
#pragma unroll
            for (int mi = 0; mi < 4; ++mi)
#pragma unroll
                for (int ni = 0; ni < 2; ++ni)
                    acc[mi][ni] = __builtin_amdgcn_mfma_f32_16x16x32_bf16(
                        af[mi], bf[ni], acc[mi][ni], 0, 0, 0);
        }

        if (more) {  // expansion VALU interleaves with MFMA tail
            expand12(xr[0].x, er[0].us);
            expand12(xr[0].y, er[0].us + 12);
            expand12(xr[1].x, er[1].us);
            expand12(xr[1].y, er[1].us + 12);
        }
    }

    // epilogue: split-K accumulate via atomics; BN folded (bias once, z==0)
#pragma unroll
    for (int ni = 0; ni < 2; ++ni) {
        int n = nb * 64 + wn * 32 + ni * 16 + l15;
        float scale = 1.0f, bias = 0.0f;
        if (FUSE_BN) {
            float sc = gamma[n] * rsqrtf(var[n] + 1e-5f);
            scale = sc;
            bias  = (z == 0) ? (beta[n] - mean[n] * sc) : 0.0f;
        }
#pragma unroll
        for (int mi = 0; mi < 4; ++mi) {
            int mb = blockM + wm * 64 + mi * 16 + q * 4;
#pragma unroll
            for (int r = 0; r < 4; ++r) {
                float v = acc[mi][ni][r];
                if (FUSE_BN) v = v * scale + bias;
                atomicAdd(&C[(size_t)(mb + r) * N + n], v);
            }
        }
    }
}

// ---------------------------------------------------------------------------
extern "C" void kernel_launch(void* const* d_in, const int* in_sizes, int n_in,
                              void* d_out, int out_size, void* d_ws, size_t ws_size,
                              hipStream_t stream) {
    const float* x     = (const float*)d_in[0];
    const float* bw0   = (const float*)d_in[2];
    const float* sw0   = (const float*)d_in[3];
    const float* bw1   = (const float*)d_in[5];
    const float* sw1   = (const float*)d_in[6];
    const float* bw2   = (const float*)d_in[8];
    const float* sw2   = (const float*)d_in[9];
    const float* gamma = (const float*)d_in[10];
    const float* beta  = (const float*)d_in[11];
    const float* mean  = (const float*)d_in[12];
    const float* var   = (const float*)d_in[13];

    char* ws = (char*)d_ws;
    ushort_t* W0 = (ushort_t*)(ws);
    ushort_t* W1 = (ushort_t*)(ws + 3145728);
    ushort_t* W2 = (ushort_t*)(ws + 9437184);
    float*    H1 = (float*)(ws + 12582912);
    float*    H2 = (float*)(ws + 29360128);
    float*    out = (float*)d_out;

    // pack weights (re-done every call; d_ws is poisoned between calls)
    // chunks = N*fin*12/8
    pack_w_kernel<<<(512 * 256 * 12 / 8 + 255) / 256, 256, 0, stream>>>(
        bw0, sw0, W0, 256, 32, 512 * 256 * 12 / 8);
    pack_w_kernel<<<(512 * 512 * 12 / 8 + 255) / 256, 256, 0, stream>>>(
        bw1, sw1, W1, 512, 64, 512 * 512 * 12 / 8);
    pack_w_kernel<<<(256 * 512 * 12 / 8 + 255) / 256, 256, 0, stream>>>(
        bw2, sw2, W2, 512, 64, 256 * 512 * 12 / 8);

    // zero accumulation targets (H1+H2 contiguous 32MB, out 8MB)
    zero_kernel<<<2048, 256, 0, stream>>>((float4*)H1, (16777216 * 2) / 16);
    zero_kernel<<<1024, 256, 0, stream>>>((float4*)out, 8388608 / 16);

    // layer 0: fin=256 (KB=32), N=512, SK=2
    {
        dim3 g(64, 8, 2);
        kan_gemm_kernel<false><<<g, 256, 0, stream>>>(x, W0, H1, 256, 512, 32, 16,
                                                      nullptr, nullptr, nullptr, nullptr);
    }
    // layer 1: fin=512 (KB=64), N=512, SK=2
    {
        dim3 g(64, 8, 2);
        kan_gemm_kernel<false><<<g, 256, 0, stream>>>(H1, W1, H2, 512, 512, 64, 32,
                                                      nullptr, nullptr, nullptr, nullptr);
    }
    // layer 2: fin=512 (KB=64), N=256, SK=4, BN fused
    {
        dim3 g(64, 4, 4);
        kan_gemm_kernel<true><<<g, 256, 0, stream>>>(H2, W2, out, 512, 256, 64, 16,
                                                     gamma, beta, mean, var);
    }
}

// Round 3
// 338.841 us; speedup vs baseline: 1.5461x; 1.5461x over previous
//
#include <hip/hip_runtime.h>
#include <hip/hip_bf16.h>
#include <cstdint>

// KAN MLP: 256->512->512->256, B=8192, cubic B-splines (uniform grid h=0.25,
// knots -1.75..1.75, 11 bases), BN at the end.
//
// Round-3: two-phase per layer (expand once per element -> bf16 A in HBM,
// then MFMA GEMM), with:
//  - GEMM BK=128 (32 MFMA/wave per barrier-pair), LDS 48 KB, tile 128x64
//  - split-K=2 every layer into separate partial buffers (NO atomics);
//    partial reduction fused into the next layer's expansion (reads P0+P1),
//    final BN-reduce kernel for the output
//  - cheap expansion: tanh-gelu (1 v_exp), direct cardinal-spline eval
//
// Workspace layout (bytes), total 146,800,640:
//   A   @ 0          : 8192*6144*2 = 100,663,296 (reused all layers)
//   W0  @ 100663296  : 3,145,728
//   W1  @ 103809024  : 6,291,456
//   W2  @ 110100480  : 3,145,728
//   P   @ 113246208  : 2 x 16,777,216 fp32 partials (L0/L1); L2 uses 2 x 8 MB

typedef unsigned short ushort_t;
typedef __bf16 bf16x8 __attribute__((ext_vector_type(8)));
typedef float f32x4 __attribute__((ext_vector_type(4)));

__device__ __forceinline__ ushort_t f2bf(float f) {
    __bf16 h = (__bf16)f;  // RNE
    return __builtin_bit_cast(ushort_t, h);
}

// async global->LDS 16B copy; LDS dest must be wave-uniform base + lane*16.
__device__ __forceinline__ void gload_lds16(const void* g, void* lds) {
    __builtin_amdgcn_global_load_lds(
        (const __attribute__((address_space(1))) unsigned int*)(uintptr_t)g,
        (__attribute__((address_space(3))) unsigned int*)(unsigned int)(uintptr_t)lds,
        16, 0, 0);
}

// x -> [gelu, b0..b10] (12 bf16). Direct cardinal cubic B-spline:
// basis_j(x) = b(xs - j), xs=(x+1.75)*4;  b(t)=f(a=|t-2|):
//   a<=1: (4-6a^2+3a^3)/6 ; 1<a<2: (2-a)^3/6 ; else 0.
__device__ __forceinline__ void expand12(float x, ushort_t* o) {
    float x3 = x * x * x;
    float y  = 0.7978845608028654f * (x + 0.044715f * x3);
    float e  = __expf(2.0f * y);
    float th = 1.0f - 2.0f / (e + 1.0f);       // tanh(y); correct limits +-1
    o[0] = f2bf(0.5f * x * (1.0f + th));
    float xs = (x + 1.75f) * 4.0f;
#pragma unroll
    for (int j = 0; j < 11; ++j) {
        float t  = xs - (float)j;
        float a  = fabsf(t - 2.0f);
        float p1 = (3.0f * a - 6.0f) * a * a + 4.0f;   // a<=1 branch
        float c  = 2.0f - a;
        float p2 = c * c * c;                          // 1<a<2 branch; <=0 for a>=2
        float v  = (a <= 1.0f) ? p1 : fmaxf(p2, 0.0f);
        o[1 + j] = f2bf(v * (1.0f / 6.0f));
    }
}

// ---------------------------------------------------------------------------
// Expansion: 2 elements/thread; optionally sums two partial inputs (split-K
// reduction of the previous layer fused in). Writes 48 B/thread (3x uint4).
// ---------------------------------------------------------------------------
template <bool SUM>
__global__ __launch_bounds__(256) void expand_kernel(
    const float* __restrict__ X0, const float* __restrict__ X1,
    ushort_t* __restrict__ A, int total2)
{
    int idx = blockIdx.x * 256 + threadIdx.x;
    if (idx >= total2) return;
    float2 h = *(const float2*)(X0 + 2 * (size_t)idx);
    if (SUM) {
        float2 h2 = *(const float2*)(X1 + 2 * (size_t)idx);
        h.x += h2.x; h.y += h2.y;
    }
    union { ushort_t us[24]; uint4 v[3]; } pk;
    expand12(h.x, pk.us);
    expand12(h.y, pk.us + 12);
    uint4* dst = (uint4*)(A + (size_t)idx * 24);
    dst[0] = pk.v[0]; dst[1] = pk.v[1]; dst[2] = pk.v[2];
}

// ---------------------------------------------------------------------------
// Weight pack (row-major): W[o][i*12+0]=base_w[o][i]; W[o][i*12+1+k]=spline_w.
// ---------------------------------------------------------------------------
__global__ __launch_bounds__(256) void pack_w_kernel(
    const float* __restrict__ bw, const float* __restrict__ sw,
    ushort_t* __restrict__ W, int total)
{
    int idx = blockIdx.x * 256 + threadIdx.x;
    if (idx >= total) return;
    union { ushort_t us[12]; uint2 v[3]; } pk;
    pk.us[0] = f2bf(bw[idx]);
    const float* s = sw + (size_t)idx * 11;
#pragma unroll
    for (int k = 0; k < 11; ++k) pk.us[1 + k] = f2bf(s[k]);
    uint2* dst = (uint2*)(W + (size_t)idx * 12);
    dst[0] = pk.v[0]; dst[1] = pk.v[1]; dst[2] = pk.v[2];
}

// ---------------------------------------------------------------------------
// GEMM: C_z[M,N] = A[M, kslice] @ W[N, kslice]^T  (bf16 in, fp32 out).
// Tile 128(M) x 64(N), BK=128, 4 waves 2x2 (wave = 64x32), split-K over
// blockIdx.z writing to C + z*M*N. XOR swizzle on 16B chunks (low 3 bits)
// keeps ds_read_b128 conflict-free; staging via global_load_lds width=16.
//   A frag: lane holds A[m=l15][k=q*8+j]; C/D: D[m=q*4+r][n=l15].
// ---------------------------------------------------------------------------
__global__ __launch_bounds__(256, 3) void gemm_kernel(
    const ushort_t* __restrict__ A,  // M x K
    const ushort_t* __restrict__ W,  // N x K
    float* __restrict__ C,           // split-K partials, z*M*N apart
    int M, int N, int K, int kcps)   // kcps = K-chunks (of 128) per split
{
    __shared__ __align__(16) ushort_t As[128 * 128];  // 32 KB
    __shared__ __align__(16) ushort_t Bs[64 * 128];   // 16 KB

    const int t   = threadIdx.x;
    const int l   = t & 63;
    const int w   = t >> 6;
    const int wm  = w >> 1;
    const int wn  = w & 1;
    const int l15 = l & 15;
    const int q   = l >> 4;
    const int blockM = blockIdx.x * 128;
    const int blockN = blockIdx.y * 64;
    const int kb0 = blockIdx.z * kcps, kb1 = kb0 + kcps;
    float* Cz = C + (size_t)blockIdx.z * M * N;

    f32x4 acc[4][2];
#pragma unroll
    for (int i = 0; i < 4; ++i)
#pragma unroll
        for (int j = 0; j < 2; ++j) acc[i][j] = (f32x4){0.f, 0.f, 0.f, 0.f};

    for (int kb = kb0; kb < kb1; ++kb) {
        const int k0 = kb << 7;
        // stage A tile: 128 rows x 16 chunks = 2048 chunks, 8/thread
#pragma unroll
        for (int it = 0; it < 8; ++it) {
            int s   = it * 256 + t;
            int row = s >> 4, c = s & 15;
            int g   = (c & 8) | ((c & 7) ^ (row & 7));
            gload_lds16(A + ((size_t)(blockM + row) * K + k0 + g * 8), &As[s * 8]);
        }
        // stage B tile: 64 rows x 16 chunks = 1024 chunks, 4/thread
#pragma unroll
        for (int it = 0; it < 4; ++it) {
            int s   = it * 256 + t;
            int row = s >> 4, c = s & 15;
            int g   = (c & 8) | ((c & 7) ^ (row & 7));
            gload_lds16(W + ((size_t)(blockN + row) * K + k0 + g * 8), &Bs[s * 8]);
        }
        __syncthreads();

        // 4 k-steps of 32: 32 MFMA/wave per barrier-pair
#pragma unroll
        for (int ks = 0; ks < 4; ++ks) {
            bf16x8 af[4], bf[2];
            const int kc = ks * 4 + q;
#pragma unroll
            for (int mi = 0; mi < 4; ++mi) {
                int m  = wm * 64 + mi * 16 + l15;
                int cs = (kc & 8) | ((kc & 7) ^ (m & 7));
                af[mi] = *(const bf16x8*)&As[(size_t)(m * 16 + cs) * 8];
            }
#pragma unroll
            for (int ni = 0; ni < 2; ++ni) {
                int n  = wn * 32 + ni * 16 + l15;
                int cs = (kc & 8) | ((kc & 7) ^ (n & 7));
                bf[ni] = *(const bf16x8*)&Bs[(size_t)(n * 16 + cs) * 8];
            }
#pragma unroll
            for (int mi = 0; mi < 4; ++mi)
#pragma unroll
                for (int ni = 0; ni < 2; ++ni)
                    acc[mi][ni] = __builtin_amdgcn_mfma_f32_16x16x32_bf16(
                        af[mi], bf[ni], acc[mi][ni], 0, 0, 0);
        }
        __syncthreads();
    }

    // epilogue: plain coalesced stores into this split's partial buffer
#pragma unroll
    for (int ni = 0; ni < 2; ++ni) {
        int n = blockN + wn * 32 + ni * 16 + l15;
#pragma unroll
        for (int mi = 0; mi < 4; ++mi) {
            int mb = blockM + wm * 64 + mi * 16 + q * 4;
#pragma unroll
            for (int r = 0; r < 4; ++r)
                Cz[(size_t)(mb + r) * N + n] = acc[mi][ni][r];
        }
    }
}

// ---------------------------------------------------------------------------
// Final: out = gamma*rsqrt(var+eps)*(P0+P1 - mean) + beta, N=256 columns.
// ---------------------------------------------------------------------------
__global__ __launch_bounds__(256) void bn_reduce_kernel(
    const float4* __restrict__ P0, const float4* __restrict__ P1,
    const float* __restrict__ gamma, const float* __restrict__ beta,
    const float* __restrict__ mean,  const float* __restrict__ var,
    float4* __restrict__ out, int n4)
{
    int i = blockIdx.x * 256 + threadIdx.x;
    if (i >= n4) return;
    float4 a = P0[i], b = P1[i];
    int nb = (i * 4) & 255;
    float4 g = *(const float4*)(gamma + nb);
    float4 be = *(const float4*)(beta + nb);
    float4 mn = *(const float4*)(mean + nb);
    float4 vr = *(const float4*)(var + nb);
    float4 o;
    o.x = g.x * rsqrtf(vr.x + 1e-5f) * (a.x + b.x - mn.x) + be.x;
    o.y = g.y * rsqrtf(vr.y + 1e-5f) * (a.y + b.y - mn.y) + be.y;
    o.z = g.z * rsqrtf(vr.z + 1e-5f) * (a.z + b.z - mn.z) + be.z;
    o.w = g.w * rsqrtf(vr.w + 1e-5f) * (a.w + b.w - mn.w) + be.w;
    out[i] = o;
}

// ---------------------------------------------------------------------------
extern "C" void kernel_launch(void* const* d_in, const int* in_sizes, int n_in,
                              void* d_out, int out_size, void* d_ws, size_t ws_size,
                              hipStream_t stream) {
    const float* x     = (const float*)d_in[0];
    const float* bw0   = (const float*)d_in[2];
    const float* sw0   = (const float*)d_in[3];
    const float* bw1   = (const float*)d_in[5];
    const float* sw1   = (const float*)d_in[6];
    const float* bw2   = (const float*)d_in[8];
    const float* sw2   = (const float*)d_in[9];
    const float* gamma = (const float*)d_in[10];
    const float* beta  = (const float*)d_in[11];
    const float* mean  = (const float*)d_in[12];
    const float* var   = (const float*)d_in[13];

    char* ws = (char*)d_ws;
    ushort_t* Abuf = (ushort_t*)(ws);
    ushort_t* W0   = (ushort_t*)(ws + 100663296);
    ushort_t* W1   = (ushort_t*)(ws + 103809024);
    ushort_t* W2   = (ushort_t*)(ws + 110100480);
    float*    P0   = (float*)(ws + 113246208);   // 16 MB partial (L0/L1)
    float*    P1   = (float*)(ws + 130023424);   // 16 MB partial (L0/L1)
    float*    Q0   = (float*)(ws + 113246208);   // 8 MB partial (L2)
    float*    Q1   = (float*)(ws + 121634816);   // 8 MB partial (L2)
    float*    out  = (float*)d_out;

    // weight packing (d_ws re-poisoned every call -> repack)
    pack_w_kernel<<<(512 * 256 + 255) / 256, 256, 0, stream>>>(bw0, sw0, W0, 512 * 256);
    pack_w_kernel<<<(512 * 512 + 255) / 256, 256, 0, stream>>>(bw1, sw1, W1, 512 * 512);
    pack_w_kernel<<<(256 * 512 + 255) / 256, 256, 0, stream>>>(bw2, sw2, W2, 256 * 512);

    // layer 0: fin=256 -> K=3072 (24 chunks, 12/split), N=512
    expand_kernel<false><<<4096, 256, 0, stream>>>(x, nullptr, Abuf, 8192 * 256 / 2);
    {
        dim3 g(64, 8, 2);
        gemm_kernel<<<g, 256, 0, stream>>>(Abuf, W0, P0, 8192, 512, 3072, 12);
    }
    // layer 1: fin=512 -> K=6144 (48 chunks, 24/split), N=512
    expand_kernel<true><<<8192, 256, 0, stream>>>(P0, P1, Abuf, 8192 * 512 / 2);
    {
        dim3 g(64, 8, 2);
        gemm_kernel<<<g, 256, 0, stream>>>(Abuf, W1, P0, 8192, 512, 6144, 24);
    }
    // layer 2: fin=512 -> K=6144, N=256
    expand_kernel<true><<<8192, 256, 0, stream>>>(P0, P1, Abuf, 8192 * 512 / 2);
    {
        dim3 g(64, 4, 2);
        gemm_kernel<<<g, 256, 0, stream>>>(Abuf, W2, Q0, 8192, 256, 6144, 24);
    }
    // BN + split-K reduce -> out
    bn_reduce_kernel<<<2048, 256, 0, stream>>>((const float4*)Q0, (const float4*)Q1,
                                               gamma, beta, mean, var,
                                               (float4*)out, 8192 * 256 / 4);
}

// Round 4
// 303.055 us; speedup vs baseline: 1.7287x; 1.1181x over previous
//
#include <hip/hip_runtime.h>
#include <hip/hip_bf16.h>
#include <cstdint>

// KAN MLP: 256->512->512->256, B=8192, cubic B-splines (uniform grid h=0.25,
// knots -1.75..1.75, 11 bases), BN at the end.
//
// Round-4: two-phase per layer (expand once per element -> bf16 A in HBM,
// then MFMA GEMM). GEMM = m97-proven structure:
//  - tile 128(M) x 128(N), BK=64, 4 waves 2x2, each wave 64x64 (4x4 acc)
//  - 32 MFMA + 16 ds_read_b128 per wave per K-chunk
//  - round-1 LDS layout (64-col tiles, 3-bit XOR chunk swizzle) -- measured
//    ZERO bank conflicts (round 3's 256B-row layout measured 4 cyc/read!)
//  - split-K into separate partial buffers (no atomics); reduction fused
//    into next layer's expand / final BN kernel.
//
// Workspace (146,800,640 bytes total -- proven available in round 1):
//   A   @ 0          : 8192*6144*2 = 100,663,296 (reused all layers)
//   W0  @ 100663296  : 3,145,728
//   W1  @ 103809024  : 6,291,456
//   W2  @ 110100480  : 3,145,728
//   P   @ 113246208  : L0/L1: 2 x 16MB fp32 partials; L2: 4 x 8MB partials

typedef unsigned short ushort_t;
typedef __bf16 bf16x8 __attribute__((ext_vector_type(8)));
typedef float f32x4 __attribute__((ext_vector_type(4)));

__device__ __forceinline__ ushort_t f2bf(float f) {
    __bf16 h = (__bf16)f;  // RNE
    return __builtin_bit_cast(ushort_t, h);
}

// async global->LDS 16B copy; LDS dest must be wave-uniform base + lane*16.
__device__ __forceinline__ void gload_lds16(const void* g, void* lds) {
    __builtin_amdgcn_global_load_lds(
        (const __attribute__((address_space(1))) unsigned int*)(uintptr_t)g,
        (__attribute__((address_space(3))) unsigned int*)(unsigned int)(uintptr_t)lds,
        16, 0, 0);
}

// x -> [gelu, b0..b10] (12 bf16). Direct cardinal cubic B-spline:
// basis_j(x) = b(xs - j), xs=(x+1.75)*4;  b(t), a=|t-2|:
//   a<=1: (4-6a^2+3a^3)/6 ; 1<a<2: (2-a)^3/6 ; else 0.
__device__ __forceinline__ void expand12(float x, ushort_t* o) {
    float x3 = x * x * x;
    float y  = 0.7978845608028654f * (x + 0.044715f * x3);
    float e  = __expf(2.0f * y);
    float th = 1.0f - 2.0f / (e + 1.0f);       // tanh(y)
    o[0] = f2bf(0.5f * x * (1.0f + th));
    float xs = (x + 1.75f) * 4.0f;
#pragma unroll
    for (int j = 0; j < 11; ++j) {
        float t  = xs - (float)j;
        float a  = fabsf(t - 2.0f);
        float p1 = (3.0f * a - 6.0f) * a * a + 4.0f;   // a<=1 branch
        float c  = 2.0f - a;
        float p2 = c * c * c;                          // 1<a<2 branch
        float v  = (a <= 1.0f) ? p1 : fmaxf(p2, 0.0f);
        o[1 + j] = f2bf(v * (1.0f / 6.0f));
    }
}

// ---------------------------------------------------------------------------
// Expansion: 2 elements/thread; optionally sums two partials (previous
// layer's split-K reduction fused in). Writes 48 B/thread.
// ---------------------------------------------------------------------------
template <bool SUM>
__global__ __launch_bounds__(256) void expand_kernel(
    const float* __restrict__ X0, const float* __restrict__ X1,
    ushort_t* __restrict__ A, int total2)
{
    int idx = blockIdx.x * 256 + threadIdx.x;
    if (idx >= total2) return;
    float2 h = *(const float2*)(X0 + 2 * (size_t)idx);
    if (SUM) {
        float2 h2 = *(const float2*)(X1 + 2 * (size_t)idx);
        h.x += h2.x; h.y += h2.y;
    }
    union { ushort_t us[24]; uint4 v[3]; } pk;
    expand12(h.x, pk.us);
    expand12(h.y, pk.us + 12);
    uint4* dst = (uint4*)(A + (size_t)idx * 24);
    dst[0] = pk.v[0]; dst[1] = pk.v[1]; dst[2] = pk.v[2];
}

// ---------------------------------------------------------------------------
// Weight pack (row-major): W[o][i*12+0]=base_w[o][i]; W[o][i*12+1+k]=spline_w.
// ---------------------------------------------------------------------------
__global__ __launch_bounds__(256) void pack_w_kernel(
    const float* __restrict__ bw, const float* __restrict__ sw,
    ushort_t* __restrict__ W, int total)
{
    int idx = blockIdx.x * 256 + threadIdx.x;
    if (idx >= total) return;
    union { ushort_t us[12]; uint2 v[3]; } pk;
    pk.us[0] = f2bf(bw[idx]);
    const float* s = sw + (size_t)idx * 11;
#pragma unroll
    for (int k = 0; k < 11; ++k) pk.us[1 + k] = f2bf(s[k]);
    uint2* dst = (uint2*)(W + (size_t)idx * 12);
    dst[0] = pk.v[0]; dst[1] = pk.v[1]; dst[2] = pk.v[2];
}

// ---------------------------------------------------------------------------
// GEMM: C_z[M,N] = A[M,kslice] @ W[N,kslice]^T (bf16 in, fp32 out).
// Tile 128x128, BK=64, 4 waves 2x2, wave = 64x64 (4x4 of 16x16x32 MFMA).
// LDS: As/Bs 128 rows x 8 chunks of 16B, chunk XOR-swizzled by row&7
// (round-1 structure, measured 0 bank conflicts).
//   A frag: lane holds A[m=l15][k=q*8+j]; C/D: D[m=q*4+r][n=l15].
// Split-K over blockIdx.z -> C + z*M*N.
// ---------------------------------------------------------------------------
__global__ __launch_bounds__(256, 2) void gemm_kernel(
    const ushort_t* __restrict__ A,  // M x K
    const ushort_t* __restrict__ W,  // N x K
    float* __restrict__ C,           // split-K partials, z*M*N apart
    int M, int N, int K, int kcps)   // kcps = 64-chunks per split
{
    __shared__ __align__(16) ushort_t As[128 * 64];  // 16 KB
    __shared__ __align__(16) ushort_t Bs[128 * 64];  // 16 KB

    const int t   = threadIdx.x;
    const int l   = t & 63;
    const int w   = t >> 6;
    const int wm  = w >> 1;
    const int wn  = w & 1;
    const int l15 = l & 15;
    const int q   = l >> 4;
    const int blockM = blockIdx.x * 128;
    const int blockN = blockIdx.y * 128;
    const int kb0 = blockIdx.z * kcps, kb1 = kb0 + kcps;
    float* Cz = C + (size_t)blockIdx.z * M * N;

    f32x4 acc[4][4];
#pragma unroll
    for (int i = 0; i < 4; ++i)
#pragma unroll
        for (int j = 0; j < 4; ++j) acc[i][j] = (f32x4){0.f, 0.f, 0.f, 0.f};

    for (int kb = kb0; kb < kb1; ++kb) {
        const int k0 = kb << 6;
        // stage A: 128 rows x 8 chunks = 1024 chunks, 4/thread
#pragma unroll
        for (int it = 0; it < 4; ++it) {
            int s   = it * 256 + t;
            int row = s >> 3, c = s & 7;
            int g   = c ^ (row & 7);
            gload_lds16(A + ((size_t)(blockM + row) * K + k0 + g * 8), &As[s * 8]);
        }
        // stage B: 128 rows x 8 chunks = 1024 chunks, 4/thread
#pragma unroll
        for (int it = 0; it < 4; ++it) {
            int s   = it * 256 + t;
            int row = s >> 3, c = s & 7;
            int g   = c ^ (row & 7);
            gload_lds16(W + ((size_t)(blockN + row) * K + k0 + g * 8), &Bs[s * 8]);
        }
        __syncthreads();

        // 2 k-steps of 32: 32 MFMA / 16 ds_read_b128 per wave per kb
#pragma unroll
        for (int ks = 0; ks < 2; ++ks) {
            const int kc = ks * 4 + q;
            bf16x8 af[4], bf[4];
#pragma unroll
            for (int mi = 0; mi < 4; ++mi) {
                int m  = wm * 64 + mi * 16 + l15;
                int cs = kc ^ (m & 7);
                af[mi] = *(const bf16x8*)&As[(size_t)(m * 8 + cs) * 8];
            }
#pragma unroll
            for (int ni = 0; ni < 4; ++ni) {
                int n  = wn * 64 + ni * 16 + l15;
                int cs = kc ^ (n & 7);
                bf[ni] = *(const bf16x8*)&Bs[(size_t)(n * 8 + cs) * 8];
            }
#pragma unroll
            for (int mi = 0; mi < 4; ++mi)
#pragma unroll
                for (int ni = 0; ni < 4; ++ni)
                    acc[mi][ni] = __builtin_amdgcn_mfma_f32_16x16x32_bf16(
                        af[mi], bf[ni], acc[mi][ni], 0, 0, 0);
        }
        __syncthreads();
    }

    // epilogue: coalesced stores into this split's partial buffer
#pragma unroll
    for (int ni = 0; ni < 4; ++ni) {
        int n = blockN + wn * 64 + ni * 16 + l15;
#pragma unroll
        for (int mi = 0; mi < 4; ++mi) {
            int mb = blockM + wm * 64 + mi * 16 + q * 4;
#pragma unroll
            for (int r = 0; r < 4; ++r)
                Cz[(size_t)(mb + r) * N + n] = acc[mi][ni][r];
        }
    }
}

// ---------------------------------------------------------------------------
// Final: out = gamma*rsqrt(var+eps)*(Q0+Q1+Q2+Q3 - mean) + beta, N=256 cols.
// ---------------------------------------------------------------------------
__global__ __launch_bounds__(256) void bn_reduce_kernel(
    const float4* __restrict__ Q0, const float4* __restrict__ Q1,
    const float4* __restrict__ Q2, const float4* __restrict__ Q3,
    const float* __restrict__ gamma, const float* __restrict__ beta,
    const float* __restrict__ mean,  const float* __restrict__ var,
    float4* __restrict__ out, int n4)
{
    int i = blockIdx.x * 256 + threadIdx.x;
    if (i >= n4) return;
    float4 a = Q0[i], b = Q1[i], c = Q2[i], d = Q3[i];
    int nb = (i * 4) & 255;
    float4 g  = *(const float4*)(gamma + nb);
    float4 be = *(const float4*)(beta + nb);
    float4 mn = *(const float4*)(mean + nb);
    float4 vr = *(const float4*)(var + nb);
    float4 o;
    o.x = g.x * rsqrtf(vr.x + 1e-5f) * (a.x + b.x + c.x + d.x - mn.x) + be.x;
    o.y = g.y * rsqrtf(vr.y + 1e-5f) * (a.y + b.y + c.y + d.y - mn.y) + be.y;
    o.z = g.z * rsqrtf(vr.z + 1e-5f) * (a.z + b.z + c.z + d.z - mn.z) + be.z;
    o.w = g.w * rsqrtf(vr.w + 1e-5f) * (a.w + b.w + c.w + d.w - mn.w) + be.w;
    out[i] = o;
}

// ---------------------------------------------------------------------------
extern "C" void kernel_launch(void* const* d_in, const int* in_sizes, int n_in,
                              void* d_out, int out_size, void* d_ws, size_t ws_size,
                              hipStream_t stream) {
    const float* x     = (const float*)d_in[0];
    const float* bw0   = (const float*)d_in[2];
    const float* sw0   = (const float*)d_in[3];
    const float* bw1   = (const float*)d_in[5];
    const float* sw1   = (const float*)d_in[6];
    const float* bw2   = (const float*)d_in[8];
    const float* sw2   = (const float*)d_in[9];
    const float* gamma = (const float*)d_in[10];
    const float* beta  = (const float*)d_in[11];
    const float* mean  = (const float*)d_in[12];
    const float* var   = (const float*)d_in[13];

    char* ws = (char*)d_ws;
    ushort_t* Abuf = (ushort_t*)(ws);
    ushort_t* W0   = (ushort_t*)(ws + 100663296);
    ushort_t* W1   = (ushort_t*)(ws + 103809024);
    ushort_t* W2   = (ushort_t*)(ws + 110100480);
    float*    P0   = (float*)(ws + 113246208);   // 16 MB (L0/L1 partials)
    float*    P1   = (float*)(ws + 130023424);   // 16 MB
    float*    Q0   = (float*)(ws + 113246208);   // 8 MB (L2 partials x4)
    float*    Q1   = (float*)(ws + 121634816);
    float*    Q2   = (float*)(ws + 130023424);
    float*    Q3   = (float*)(ws + 138412032);
    float*    out  = (float*)d_out;

    // weight packing (d_ws re-poisoned every call -> repack)
    pack_w_kernel<<<(512 * 256 + 255) / 256, 256, 0, stream>>>(bw0, sw0, W0, 512 * 256);
    pack_w_kernel<<<(512 * 512 + 255) / 256, 256, 0, stream>>>(bw1, sw1, W1, 512 * 512);
    pack_w_kernel<<<(256 * 512 + 255) / 256, 256, 0, stream>>>(bw2, sw2, W2, 256 * 512);

    // layer 0: K=3072 (48 chunks, 24/split), N=512, SK=2
    expand_kernel<false><<<4096, 256, 0, stream>>>(x, nullptr, Abuf, 8192 * 256 / 2);
    {
        dim3 g(64, 4, 2);
        gemm_kernel<<<g, 256, 0, stream>>>(Abuf, W0, P0, 8192, 512, 3072, 24);
    }
    // layer 1: K=6144 (96 chunks, 48/split), N=512, SK=2
    expand_kernel<true><<<8192, 256, 0, stream>>>(P0, P1, Abuf, 8192 * 512 / 2);
    {
        dim3 g(64, 4, 2);
        gemm_kernel<<<g, 256, 0, stream>>>(Abuf, W1, P0, 8192, 512, 6144, 48);
    }
    // layer 2: K=6144 (96 chunks, 24/split), N=256, SK=4
    expand_kernel<true><<<8192, 256, 0, stream>>>(P0, P1, Abuf, 8192 * 512 / 2);
    {
        dim3 g(64, 2, 4);
        gemm_kernel<<<g, 256, 0, stream>>>(Abuf, W2, Q0, 8192, 256, 6144, 24);
    }
    // BN + split-K reduce -> out
    bn_reduce_kernel<<<2048, 256, 0, stream>>>(
        (const float4*)Q0, (const float4*)Q1, (const float4*)Q2, (const float4*)Q3,
        gamma, beta, mean, var, (float4*)out, 8192 * 256 / 4);
}